// Round 4
// baseline (179.328 us; speedup 1.0000x reference)
//
#include <hip/hip_runtime.h>

#define NB 4
#define NC 6
#define NF 257
#define NT 2000
#define NG (NB * NF)        // 1028 (b,f) groups
#define NPAIR 15
#define NACC 74             // [0..5] s_diag, [6..11] n_diag, [12+4p..] s_re,s_im,n_re,n_im, [72] sum_ms, [73] sum_mn
#define NCHUNK 2
#define TCH (NT / NCHUNK)   // 1000 t per chunk
#define NP4 (TCH / 4)       // 250 float4 positions per chunk
#define BLK 256
#define CS  (NF * NT)       // channel stride (floats)
#define CS4 (CS / 4)        // channel stride (float4)

typedef float nfloat4 __attribute__((ext_vector_type(4)));  // native vec for nontemporal builtins

// ---------------- Kernel A: raw weighted PSD partials per (group, chunk) ----
// One float4 (4 t's) per thread, single load burst -> max MLP.
__global__ __launch_bounds__(BLK) void psd_kernel(
    const float* __restrict__ sr, const float* __restrict__ si,
    const float* __restrict__ ms, const float* __restrict__ mn,
    float* __restrict__ wsp)
{
    constexpr int PC[NPAIR] = {0,0,0,0,0,1,1,1,1,2,2,2,3,3,4};
    constexpr int PE[NPAIR] = {1,2,3,4,5,2,3,4,5,3,4,5,4,5,5};

    const int bx = blockIdx.x;
    const int g  = bx >> 1;
    const int b  = g / NF;
    const int f  = g - b * NF;
    const int tb = (bx & 1) * TCH;
    const int sbase = b * NC * CS + f * NT + tb;
    const int mbase = g * NT + tb;

    const float4* s4r = (const float4*)(sr + sbase);
    const float4* s4i = (const float4*)(si + sbase);
    const float4* m4s = (const float4*)(ms + mbase);
    const float4* m4n = (const float4*)(mn + mbase);

    float acc[NACC];
    #pragma unroll
    for (int i = 0; i < NACC; i++) acc[i] = 0.f;

    const int p = threadIdx.x;
    if (p < NP4) {
        float wms[4], wmn[4], rr[NC][4], ii[NC][4];
        {
            const float4 t0 = m4s[p];
            wms[0] = t0.x; wms[1] = t0.y; wms[2] = t0.z; wms[3] = t0.w;
            const float4 t1 = m4n[p];
            wmn[0] = t1.x; wmn[1] = t1.y; wmn[2] = t1.z; wmn[3] = t1.w;
        }
        #pragma unroll
        for (int c = 0; c < NC; c++) {
            const float4 tr = s4r[c * CS4 + p];
            rr[c][0] = tr.x; rr[c][1] = tr.y; rr[c][2] = tr.z; rr[c][3] = tr.w;
            const float4 ti = s4i[c * CS4 + p];
            ii[c][0] = ti.x; ii[c][1] = ti.y; ii[c][2] = ti.z; ii[c][3] = ti.w;
        }
        acc[72] = wms[0] + wms[1] + wms[2] + wms[3];
        acc[73] = wmn[0] + wmn[1] + wmn[2] + wmn[3];
        #pragma unroll
        for (int c = 0; c < NC; c++) {
            #pragma unroll
            for (int k = 0; k < 4; k++) {
                const float d = rr[c][k] * rr[c][k] + ii[c][k] * ii[c][k];
                acc[c]     += d * wms[k];
                acc[6 + c] += d * wmn[k];
            }
        }
        #pragma unroll
        for (int q = 0; q < NPAIR; q++) {
            const int c = PC[q], e = PE[q];
            #pragma unroll
            for (int k = 0; k < 4; k++) {
                const float cr = rr[c][k] * rr[e][k] + ii[c][k] * ii[e][k];
                const float ci = ii[c][k] * rr[e][k] - rr[c][k] * ii[e][k];
                acc[12 + 4 * q + 0] += cr * wms[k];
                acc[12 + 4 * q + 1] += ci * wms[k];
                acc[12 + 4 * q + 2] += cr * wmn[k];
                acc[12 + 4 * q + 3] += ci * wmn[k];
            }
        }
    }

    // 3-stage shuffle: lane l<8 holds sum over lanes {l, l+8, ..., l+56}
    #pragma unroll
    for (int i = 0; i < NACC; i++) {
        float v = acc[i];
        v += __shfl_down(v, 32);
        v += __shfl_down(v, 16);
        v += __shfl_down(v, 8);
        acc[i] = v;
    }

    __shared__ float red[32][NACC];
    const int wid  = threadIdx.x >> 6;
    const int lane = threadIdx.x & 63;
    if (lane < 8) {
        #pragma unroll
        for (int i = 0; i < NACC; i++) red[wid * 8 + lane][i] = acc[i];
    }
    __syncthreads();

    if (threadIdx.x < NACC) {
        float s = 0.f;
        #pragma unroll
        for (int r = 0; r < 32; r++) s += red[r][threadIdx.x];
        wsp[bx * NACC + threadIdx.x] = s;
    }
}

// ---------------- Kernel B: one thread per (b,f) — combine + 6x6 solve ------
__global__ void solve_kernel(const float* __restrict__ wsp, float* __restrict__ wsw)
{
    const int gid = blockIdx.x * 64 + threadIdx.x;
    if (gid >= NG) return;

    constexpr int PC[NPAIR] = {0,0,0,0,0,1,1,1,1,2,2,2,3,3,4};
    constexpr int PE[NPAIR] = {1,2,3,4,5,2,3,4,5,3,4,5,4,5,5};

    const float* p0 = wsp + (2 * gid) * NACC;
    const float* p1 = p0 + NACC;
    float fin[NACC];
    #pragma unroll
    for (int i = 0; i < NACC; i++) fin[i] = p0[i] + p1[i];

    const float invS = 1.f / (fin[72] + 1e-15f);
    const float invN = 1.f / (fin[73] + 1e-15f);

    float Ar[NC][NC], Ai[NC][NC], Br[NC][NC], Bi[NC][NC];
    #pragma unroll
    for (int c = 0; c < NC; c++) {
        Br[c][c] = fin[c] * invS;     Bi[c][c] = 0.f;
        Ar[c][c] = fin[6 + c] * invN; Ai[c][c] = 0.f;
    }
    #pragma unroll
    for (int q = 0; q < NPAIR; q++) {
        const int c = PC[q], e = PE[q];
        const float sre = fin[12 + 4 * q + 0] * invS;
        const float sim = fin[12 + 4 * q + 1] * invS;
        const float nre = fin[12 + 4 * q + 2] * invN;
        const float nim = fin[12 + 4 * q + 3] * invN;
        Br[c][e] = sre;  Bi[c][e] = sim;
        Br[e][c] = sre;  Bi[e][c] = -sim;
        Ar[c][e] = nre;  Ai[c][e] = nim;
        Ar[e][c] = nre;  Ai[e][c] = -nim;
    }

    float trn = 0.f;
    #pragma unroll
    for (int c = 0; c < NC; c++) trn += Ar[c][c];
    const float eps = trn * 1e-7f + 1e-8f;
    #pragma unroll
    for (int c = 0; c < NC; c++) Ar[c][c] += eps;

    // Forward elimination (no pivoting: A is HPD)
    #pragma unroll
    for (int k = 0; k < NC; k++) {
        const float dr = Ar[k][k], di = Ai[k][k];
        const float idn = 1.f / (dr * dr + di * di);
        const float pr = dr * idn, pi = -di * idn;
        #pragma unroll
        for (int i2 = k + 1; i2 < NC; i2++) {
            const float fr = Ar[i2][k] * pr - Ai[i2][k] * pi;
            const float fi = Ar[i2][k] * pi + Ai[i2][k] * pr;
            #pragma unroll
            for (int j = k + 1; j < NC; j++) {
                Ar[i2][j] -= fr * Ar[k][j] - fi * Ai[k][j];
                Ai[i2][j] -= fr * Ai[k][j] + fi * Ar[k][j];
            }
            #pragma unroll
            for (int j = 0; j < NC; j++) {
                Br[i2][j] -= fr * Br[k][j] - fi * Bi[k][j];
                Bi[i2][j] -= fr * Bi[k][j] + fi * Br[k][j];
            }
        }
    }
    // Back substitution, in place into B (B becomes X)
    #pragma unroll
    for (int k = NC - 1; k >= 0; k--) {
        const float dr = Ar[k][k], di = Ai[k][k];
        const float idn = 1.f / (dr * dr + di * di);
        const float pr = dr * idn, pi = -di * idn;
        #pragma unroll
        for (int j = 0; j < NC; j++) {
            float xr = Br[k][j], xi = Bi[k][j];
            #pragma unroll
            for (int m = k + 1; m < NC; m++) {
                xr -= Ar[k][m] * Br[m][j] - Ai[k][m] * Bi[m][j];
                xi -= Ar[k][m] * Bi[m][j] + Ai[k][m] * Br[m][j];
            }
            Br[k][j] = xr * pr - xi * pi;
            Bi[k][j] = xr * pi + xi * pr;
        }
    }

    float trr = 1e-8f, tri = 0.f;   // TIK_EPS on real part of trace
    #pragma unroll
    for (int c = 0; c < NC; c++) { trr += Br[c][c]; tri += Bi[c][c]; }
    const float idn = 1.f / (trr * trr + tri * tri);
    #pragma unroll
    for (int c = 0; c < NC; c++) {
        const float xr = Br[c][0], xi = Bi[c][0];
        const float wre = (xr * trr + xi * tri) * idn;
        const float wim = (xi * trr - xr * tri) * idn;
        wsw[gid * 12 + c]     = wre;    // conj(w): real
        wsw[gid * 12 + 6 + c] = -wim;   // conj(w): imag
    }
}

// ---------------- Kernel C: enh[t] = sum_c conj(w[c]) * spec[c,t] -----------
__global__ __launch_bounds__(BLK) void apply_kernel(
    const float* __restrict__ sr, const float* __restrict__ si,
    const float* __restrict__ wsw, float* __restrict__ out)
{
    const int bx = blockIdx.x;
    const int g  = bx >> 1;
    const int b  = g / NF;
    const int f  = g - b * NF;
    const int tb = (bx & 1) * TCH;
    const int sbase = b * NC * CS + f * NT + tb;

    const float4* s4r = (const float4*)(sr + sbase);
    const float4* s4i = (const float4*)(si + sbase);

    float wr[NC], wi[NC];
    #pragma unroll
    for (int c = 0; c < NC; c++) {
        wr[c] = wsw[g * 12 + c];
        wi[c] = wsw[g * 12 + 6 + c];
    }

    nfloat4* o4 = (nfloat4*)(out + 2 * (g * NT + tb));

    const int p = threadIdx.x;
    if (p < NP4) {
        float rr[NC][4], ii[NC][4];
        #pragma unroll
        for (int c = 0; c < NC; c++) {
            const float4 tr = s4r[c * CS4 + p];
            rr[c][0] = tr.x; rr[c][1] = tr.y; rr[c][2] = tr.z; rr[c][3] = tr.w;
            const float4 ti = s4i[c * CS4 + p];
            ii[c][0] = ti.x; ii[c][1] = ti.y; ii[c][2] = ti.z; ii[c][3] = ti.w;
        }
        float er[4], ei[4];
        #pragma unroll
        for (int k = 0; k < 4; k++) {
            float a = 0.f, bb = 0.f;
            #pragma unroll
            for (int c = 0; c < NC; c++) {
                a  += wr[c] * rr[c][k] - wi[c] * ii[c][k];
                bb += wr[c] * ii[c][k] + wi[c] * rr[c][k];
            }
            er[k] = a; ei[k] = bb;
        }
        nfloat4 o0 = {er[0], ei[0], er[1], ei[1]};
        nfloat4 o1 = {er[2], ei[2], er[3], ei[3]};
        __builtin_nontemporal_store(o0, &o4[2 * p]);
        __builtin_nontemporal_store(o1, &o4[2 * p + 1]);
    }
}

extern "C" void kernel_launch(void* const* d_in, const int* in_sizes, int n_in,
                              void* d_out, int out_size, void* d_ws, size_t ws_size,
                              hipStream_t stream) {
    const float* sr = (const float*)d_in[0];
    const float* si = (const float*)d_in[1];
    const float* ms = (const float*)d_in[2];
    const float* mn = (const float*)d_in[3];
    float* out = (float*)d_out;

    float* wsp = (float*)d_ws;                       // [NG*NCHUNK][NACC] partials
    float* wsw = wsp + NG * NCHUNK * NACC;           // [NG][12] conj(w)

    psd_kernel<<<NG * NCHUNK, BLK, 0, stream>>>(sr, si, ms, mn, wsp);
    solve_kernel<<<(NG + 63) / 64, 64, 0, stream>>>(wsp, wsw);
    apply_kernel<<<NG * NCHUNK, BLK, 0, stream>>>(sr, si, wsw, out);
}

// Round 5
// 176.034 us; speedup vs baseline: 1.0187x; 1.0187x over previous
//
#include <hip/hip_runtime.h>

#define NB 4
#define NC 6
#define NF 257
#define NT 2000
#define NG (NB * NF)        // 1028 (b,f) groups
#define NPAIR 15
#define NACC 74             // [0..5] s_diag, [6..11] n_diag, [12+4q..] s_re,s_im,n_re,n_im, [72] sum_ms, [73] sum_mn
#define BLK 256
#define CS  (NF * NT)       // channel stride (floats)
#define CS4 (CS / 4)        // channel stride (float4)
#define NP4G (NT / 4)       // 500 float4 positions per group
#define HALF4 (NP4G / 2)    // 250

typedef float nfloat4 __attribute__((ext_vector_type(4)));  // native vec for nontemporal builtins

__device__ __forceinline__ void psd_acc_pos(
    const float4* __restrict__ s4r, const float4* __restrict__ s4i,
    const float4* __restrict__ m4s, const float4* __restrict__ m4n,
    int p, float (&acc)[NACC])
{
    constexpr int PC[NPAIR] = {0,0,0,0,0,1,1,1,1,2,2,2,3,3,4};
    constexpr int PE[NPAIR] = {1,2,3,4,5,2,3,4,5,3,4,5,4,5,5};

    float wms[4], wmn[4], rr[NC][4], ii[NC][4];
    {
        const float4 t0 = m4s[p];
        wms[0] = t0.x; wms[1] = t0.y; wms[2] = t0.z; wms[3] = t0.w;
        const float4 t1 = m4n[p];
        wmn[0] = t1.x; wmn[1] = t1.y; wmn[2] = t1.z; wmn[3] = t1.w;
    }
    #pragma unroll
    for (int c = 0; c < NC; c++) {
        const float4 tr = s4r[c * CS4 + p];
        rr[c][0] = tr.x; rr[c][1] = tr.y; rr[c][2] = tr.z; rr[c][3] = tr.w;
        const float4 ti = s4i[c * CS4 + p];
        ii[c][0] = ti.x; ii[c][1] = ti.y; ii[c][2] = ti.z; ii[c][3] = ti.w;
    }
    #pragma unroll
    for (int k = 0; k < 4; k++) { acc[72] += wms[k]; acc[73] += wmn[k]; }
    #pragma unroll
    for (int c = 0; c < NC; c++) {
        #pragma unroll
        for (int k = 0; k < 4; k++) {
            const float d = rr[c][k] * rr[c][k] + ii[c][k] * ii[c][k];
            acc[c]     += d * wms[k];
            acc[6 + c] += d * wmn[k];
        }
    }
    #pragma unroll
    for (int q = 0; q < NPAIR; q++) {
        const int c = PC[q], e = PE[q];
        #pragma unroll
        for (int k = 0; k < 4; k++) {
            const float cr = rr[c][k] * rr[e][k] + ii[c][k] * ii[e][k];
            const float ci = ii[c][k] * rr[e][k] - rr[c][k] * ii[e][k];
            acc[12 + 4 * q + 0] += cr * wms[k];
            acc[12 + 4 * q + 1] += ci * wms[k];
            acc[12 + 4 * q + 2] += cr * wmn[k];
            acc[12 + 4 * q + 3] += ci * wmn[k];
        }
    }
}

// ---------------- Kernel A: raw weighted PSDs, one block per (b,f) ----------
__global__ __launch_bounds__(BLK) void psd_kernel(
    const float* __restrict__ sr, const float* __restrict__ si,
    const float* __restrict__ ms, const float* __restrict__ mn,
    float* __restrict__ wsp)
{
    const int g  = blockIdx.x;
    const int b  = g / NF;
    const int f  = g - b * NF;
    const int sbase = b * NC * CS + f * NT;
    const int mbase = g * NT;

    const float4* s4r = (const float4*)(sr + sbase);
    const float4* s4i = (const float4*)(si + sbase);
    const float4* m4s = (const float4*)(ms + mbase);
    const float4* m4n = (const float4*)(mn + mbase);

    float acc[NACC];
    #pragma unroll
    for (int i = 0; i < NACC; i++) acc[i] = 0.f;

    const int p = threadIdx.x;
    if (p < HALF4) {
        // Both positions in the same basic block -> scheduler can merge the
        // two 14-load bursts and overlap loads with compute.
        psd_acc_pos(s4r, s4i, m4s, m4n, p, acc);
        psd_acc_pos(s4r, s4i, m4s, m4n, p + HALF4, acc);
    }

    // 3-stage shuffle: lane l<8 holds sum over lanes {l, l+8, ..., l+56}
    #pragma unroll
    for (int i = 0; i < NACC; i++) {
        float v = acc[i];
        v += __shfl_down(v, 32);
        v += __shfl_down(v, 16);
        v += __shfl_down(v, 8);
        acc[i] = v;
    }

    __shared__ float red[32][NACC];
    const int wid  = threadIdx.x >> 6;
    const int lane = threadIdx.x & 63;
    if (lane < 8) {
        #pragma unroll
        for (int i = 0; i < NACC; i++) red[wid * 8 + lane][i] = acc[i];
    }
    __syncthreads();

    if (threadIdx.x < NACC) {
        float s = 0.f;
        #pragma unroll
        for (int r = 0; r < 32; r++) s += red[r][threadIdx.x];
        wsp[g * NACC + threadIdx.x] = s;
    }
}

// ---------------- Kernel B: one thread per (b,f) — LU + column solves -------
// __launch_bounds__(64,1): allow up to ~512 VGPRs so nothing spills to scratch
// (round-4 profile showed VGPR=64 + massive scratch spills -> 49 us).
__global__ __launch_bounds__(64, 1) void solve_kernel(
    const float* __restrict__ wsp, float* __restrict__ wsw)
{
    const int gid = blockIdx.x * 64 + threadIdx.x;
    if (gid >= NG) return;

    constexpr int PC[NPAIR] = {0,0,0,0,0,1,1,1,1,2,2,2,3,3,4};
    constexpr int PE[NPAIR] = {1,2,3,4,5,2,3,4,5,3,4,5,4,5,5};
    // q index for pair (i,j), i<j
    constexpr int QIDX[NC][NC] = {
        {-1, 0, 1, 2, 3, 4},
        {-1,-1, 5, 6, 7, 8},
        {-1,-1,-1, 9,10,11},
        {-1,-1,-1,-1,12,13},
        {-1,-1,-1,-1,-1,14},
        {-1,-1,-1,-1,-1,-1}};

    float fin[NACC];
    #pragma unroll
    for (int i = 0; i < NACC; i++) fin[i] = wsp[gid * NACC + i];

    const float invS = 1.f / (fin[72] + 1e-15f);
    const float invN = 1.f / (fin[73] + 1e-15f);

    // A = normalized psd_n + eps*I
    float Ar[NC][NC], Ai[NC][NC];
    #pragma unroll
    for (int c = 0; c < NC; c++) { Ar[c][c] = fin[6 + c] * invN; Ai[c][c] = 0.f; }
    #pragma unroll
    for (int q = 0; q < NPAIR; q++) {
        const int c = PC[q], e = PE[q];
        const float nre = fin[12 + 4 * q + 2] * invN;
        const float nim = fin[12 + 4 * q + 3] * invN;
        Ar[c][e] = nre;  Ai[c][e] = nim;
        Ar[e][c] = nre;  Ai[e][c] = -nim;
    }
    {
        float trn = 0.f;
        #pragma unroll
        for (int c = 0; c < NC; c++) trn += Ar[c][c];
        const float eps = trn * 1e-7f + 1e-8f;
        #pragma unroll
        for (int c = 0; c < NC; c++) Ar[c][c] += eps;
    }

    // In-place unpivoted LU: L (unit diag) below, U on/above.
    #pragma unroll
    for (int k = 0; k < NC; k++) {
        const float dr = Ar[k][k], di = Ai[k][k];
        const float idn = 1.f / (dr * dr + di * di);
        const float pr = dr * idn, pi = -di * idn;
        #pragma unroll
        for (int i = k + 1; i < NC; i++) {
            const float lr = Ar[i][k] * pr - Ai[i][k] * pi;
            const float li = Ar[i][k] * pi + Ai[i][k] * pr;
            Ar[i][k] = lr; Ai[i][k] = li;
            #pragma unroll
            for (int j = k + 1; j < NC; j++) {
                Ar[i][j] -= lr * Ar[k][j] - li * Ai[k][j];
                Ai[i][j] -= lr * Ai[k][j] + li * Ar[k][j];
            }
        }
    }

    // Column-by-column solve of A x = b_j (b_j = col j of normalized psd_s).
    float trr = 1e-8f, tri = 0.f;   // TIK_EPS on real part of trace
    float w0r[NC], w0i[NC];
    #pragma unroll
    for (int j = 0; j < NC; j++) {
        float xr[NC], xi[NC];
        #pragma unroll
        for (int i = 0; i < NC; i++) {
            if (i == j)      { xr[i] = fin[j] * invS;                      xi[i] = 0.f; }
            else if (i < j)  { const int q = QIDX[i][j];
                               xr[i] = fin[12 + 4 * q] * invS;  xi[i] =  fin[13 + 4 * q] * invS; }
            else             { const int q = QIDX[j][i];
                               xr[i] = fin[12 + 4 * q] * invS;  xi[i] = -fin[13 + 4 * q] * invS; }
        }
        // forward: y_i = b_i - sum_{k<i} L_ik y_k
        #pragma unroll
        for (int i = 1; i < NC; i++) {
            #pragma unroll
            for (int k = 0; k < NC - 1; k++) if (k < i) {
                xr[i] -= Ar[i][k] * xr[k] - Ai[i][k] * xi[k];
                xi[i] -= Ar[i][k] * xi[k] + Ai[i][k] * xr[k];
            }
        }
        // back: x_i = (y_i - sum_{k>i} U_ik x_k) / U_ii
        #pragma unroll
        for (int i = NC - 1; i >= 0; i--) {
            #pragma unroll
            for (int k = 0; k < NC; k++) if (k > i) {
                xr[i] -= Ar[i][k] * xr[k] - Ai[i][k] * xi[k];
                xi[i] -= Ar[i][k] * xi[k] + Ai[i][k] * xr[k];
            }
            const float dr = Ar[i][i], di = Ai[i][i];
            const float idn = 1.f / (dr * dr + di * di);
            const float pr = dr * idn, pi = -di * idn;
            const float tr0 = xr[i] * pr - xi[i] * pi;
            xi[i] = xr[i] * pi + xi[i] * pr;
            xr[i] = tr0;
        }
        trr += xr[j]; tri += xi[j];
        if (j == 0) {
            #pragma unroll
            for (int i = 0; i < NC; i++) { w0r[i] = xr[i]; w0i[i] = xi[i]; }
        }
    }

    const float idn = 1.f / (trr * trr + tri * tri);
    #pragma unroll
    for (int c = 0; c < NC; c++) {
        const float wre = (w0r[c] * trr + w0i[c] * tri) * idn;
        const float wim = (w0i[c] * trr - w0r[c] * tri) * idn;
        wsw[gid * 12 + c]     = wre;    // conj(w): real
        wsw[gid * 12 + 6 + c] = -wim;   // conj(w): imag
    }
}

// ---------------- Kernel C: enh[t] = sum_c conj(w[c]) * spec[c,t] -----------
__global__ __launch_bounds__(BLK) void apply_kernel(
    const float* __restrict__ sr, const float* __restrict__ si,
    const float* __restrict__ wsw, float* __restrict__ out)
{
    const int bx = blockIdx.x;
    const int g  = bx >> 1;
    const int b  = g / NF;
    const int f  = g - b * NF;
    const int tb = (bx & 1) * (NT / 2);
    const int sbase = b * NC * CS + f * NT + tb;

    const float4* s4r = (const float4*)(sr + sbase);
    const float4* s4i = (const float4*)(si + sbase);

    float wr[NC], wi[NC];
    #pragma unroll
    for (int c = 0; c < NC; c++) {
        wr[c] = wsw[g * 12 + c];
        wi[c] = wsw[g * 12 + 6 + c];
    }

    nfloat4* o4 = (nfloat4*)(out + 2 * (g * NT + tb));

    const int p = threadIdx.x;
    if (p < HALF4) {
        float rr[NC][4], ii[NC][4];
        #pragma unroll
        for (int c = 0; c < NC; c++) {
            const float4 tr = s4r[c * CS4 + p];
            rr[c][0] = tr.x; rr[c][1] = tr.y; rr[c][2] = tr.z; rr[c][3] = tr.w;
            const float4 ti = s4i[c * CS4 + p];
            ii[c][0] = ti.x; ii[c][1] = ti.y; ii[c][2] = ti.z; ii[c][3] = ti.w;
        }
        float er[4], ei[4];
        #pragma unroll
        for (int k = 0; k < 4; k++) {
            float a = 0.f, bb = 0.f;
            #pragma unroll
            for (int c = 0; c < NC; c++) {
                a  += wr[c] * rr[c][k] - wi[c] * ii[c][k];
                bb += wr[c] * ii[c][k] + wi[c] * rr[c][k];
            }
            er[k] = a; ei[k] = bb;
        }
        nfloat4 o0 = {er[0], ei[0], er[1], ei[1]};
        nfloat4 o1 = {er[2], ei[2], er[3], ei[3]};
        __builtin_nontemporal_store(o0, &o4[2 * p]);
        __builtin_nontemporal_store(o1, &o4[2 * p + 1]);
    }
}

extern "C" void kernel_launch(void* const* d_in, const int* in_sizes, int n_in,
                              void* d_out, int out_size, void* d_ws, size_t ws_size,
                              hipStream_t stream) {
    const float* sr = (const float*)d_in[0];
    const float* si = (const float*)d_in[1];
    const float* ms = (const float*)d_in[2];
    const float* mn = (const float*)d_in[3];
    float* out = (float*)d_out;

    float* wsp = (float*)d_ws;                       // [NG][NACC] group PSD sums
    float* wsw = wsp + NG * NACC;                    // [NG][12] conj(w)

    psd_kernel<<<NG, BLK, 0, stream>>>(sr, si, ms, mn, wsp);
    solve_kernel<<<(NG + 63) / 64, 64, 0, stream>>>(wsp, wsw);
    apply_kernel<<<NG * 2, BLK, 0, stream>>>(sr, si, wsw, out);
}